// Round 6
// baseline (707.097 us; speedup 1.0000x reference)
//
#include <hip/hip_runtime.h>
#include <hip/hip_bf16.h>

#define HH 50
#define TT 1024
#define BT 16            // batch tile per block (MFMA M)
#define NB (2048 / BT)   // 128 blocks
#define CHUNK 256        // x staging chunk (timesteps)
#define CM (CHUNK - 1)
#define XST 260          // x LDS row stride (floats)
#define HST 72           // h LDS base row stride (bf16 elems)
#define HBSZ 1184        // h buffer size incl. row-8..15 +16 offset

#define L2E 1.4426950408889634f   // log2(e)
#define K2E 2.8853900817779268f   // 2*log2(e)

typedef __bf16 bf16x8 __attribute__((ext_vector_type(8)));
typedef float f32x4 __attribute__((ext_vector_type(4)));

union BF8 { bf16x8 v; unsigned short u[8]; };

__device__ __forceinline__ unsigned short f2bf(float f) {
    unsigned int u = __builtin_bit_cast(unsigned int, f);
    u += 0x7fffu + ((u >> 16) & 1u);   // RNE
    return (unsigned short)(u >> 16);
}
__device__ __forceinline__ float rcp_f(float x) { return __builtin_amdgcn_rcpf(x); }
__device__ __forceinline__ float exp2_f(float x) { return __builtin_amdgcn_exp2f(x); }
__device__ __forceinline__ float sigm(float x) { return rcp_f(1.0f + __expf(-x)); }
__device__ __forceinline__ float tanh_f(float x) {
    return __builtin_fmaf(-2.0f, rcp_f(1.0f + __expf(2.0f * x)), 1.0f);
}
// bank-conflict-free h layout: rows 8-15 shifted +16 elems so the 4 quads'
// simultaneous row-writes land on banks {0,8,16,24}+4r instead of 4-way
__device__ __forceinline__ int hoff(int row) {
    return row * HST + 16 * ((row >> 3) & 1);
}

__global__ __launch_bounds__(256, 1) void lstm_mfma_kernel(
    const float* __restrict__ x,
    const float* __restrict__ wih1, const float* __restrict__ whh1,
    const float* __restrict__ bih1, const float* __restrict__ bhh1,
    const float* __restrict__ wih2,
    const float* __restrict__ bih2, const float* __restrict__ bhh2,
    const float* __restrict__ fcw,  const float* __restrict__ fcb,
    float* __restrict__ out)
{
    __shared__ float xs[BT * XST];                 // 16.6 KB
    __shared__ unsigned short hb[2][HBSZ];         // 4.7 KB
    __shared__ float h2s[BT * 52];                 // 3.3 KB

    const int tid  = threadIdx.x;
    const int wv   = tid >> 6;        // 0..3 = j-tile
    const int lane = tid & 63;
    const int l16  = lane & 15;
    const int quad = lane >> 4;
    const int j    = wv * 16 + l16;   // padded gate sub-index 0..63
    const bool jv  = (j < HH);
    const int b0   = blockIdx.x * BT;

    // gate scale folding: i,f,o rows * -log2e  (A=e^{-a}=exp2(acc'))
    //                     g row * +2*log2e     (G=e^{2a}=exp2(acc'))
    const float gsc[4] = { -L2E, -L2E, K2E, -L2E };

    // ---- persistent per-lane weights: Whh B-frags (bf16, pre-scaled) ----
    BF8 bw[4][2];
    float wihS[4], biasS[4];
    #pragma unroll
    for (int t4 = 0; t4 < 4; ++t4) {
        const int row = t4 * HH + j;
        const float s = gsc[t4];
        #pragma unroll
        for (int kk = 0; kk < 2; ++kk)
            #pragma unroll
            for (int e = 0; e < 8; ++e) {
                const int k = kk * 32 + quad * 8 + e;
                bw[t4][kk].u[e] = f2bf((jv && k < HH) ? s * whh1[row * HH + k] : 0.0f);
            }
        wihS[t4]  = jv ? s * wih1[row] : 0.0f;
        biasS[t4] = jv ? s * (bih1[row] + bhh1[row]) : 0.0f;
    }

    for (int i = tid; i < HBSZ; i += 256) hb[0][i] = 0;

    float c0 = 0.f, c1 = 0.f, c2 = 0.f, c3 = 0.f;   // c' = 2*log2e * c
    unsigned short* cur = hb[0];
    unsigned short* nxt = hb[1];

    const f32x4 zed = {0.f, 0.f, 0.f, 0.f};
    f32x4 iv[4];                                    // pre-computed x*wih+bias

    const int rdA = hoff(l16) + quad * 8;           // A-frag read offsets
    const int rdB = rdA + 32;

    for (int t = 0; t < TT; ++t) {
        if ((t & CM) == 0) {
            for (int i = tid; i < BT * (CHUNK / 4); i += 256) {
                const int r = i >> 6, c4 = i & 63;
                const float4 xv = ((const float4*)x)[((b0 + r) * TT + t) / 4 + c4];
                *(float4*)&xs[r * XST + c4 * 4] = xv;
            }
            __syncthreads();   // xs visible (covers hb zeroing at t==0)
            {
                const float xv0 = xs[(quad * 4 + 0) * XST];
                const float xv1 = xs[(quad * 4 + 1) * XST];
                const float xv2 = xs[(quad * 4 + 2) * XST];
                const float xv3 = xs[(quad * 4 + 3) * XST];
                #pragma unroll
                for (int t4 = 0; t4 < 4; ++t4) {
                    iv[t4][0] = __builtin_fmaf(xv0, wihS[t4], biasS[t4]);
                    iv[t4][1] = __builtin_fmaf(xv1, wihS[t4], biasS[t4]);
                    iv[t4][2] = __builtin_fmaf(xv2, wihS[t4], biasS[t4]);
                    iv[t4][3] = __builtin_fmaf(xv3, wihS[t4], biasS[t4]);
                }
            }
        }

        // A-frags for h_t — first thing after the barrier
        const bf16x8 a0 = *(const bf16x8*)&cur[rdA];
        const bf16x8 a1 = *(const bf16x8*)&cur[rdB];

        // split-C: two INDEPENDENT MFMAs per gate type, summed after
        f32x4 acc[4];
        #pragma unroll
        for (int t4 = 0; t4 < 4; ++t4) {
            const f32x4 pA = __builtin_amdgcn_mfma_f32_16x16x32_bf16(a0, bw[t4][0].v, iv[t4], 0, 0, 0);
            const f32x4 pB = __builtin_amdgcn_mfma_f32_16x16x32_bf16(a1, bw[t4][1].v, zed, 0, 0, 0);
            acc[t4] = pA + pB;
        }

        // elementwise; everything hoisted off the c-critical-path
        #pragma unroll
        for (int rr = 0; rr < 4; ++rr) {
            float& cc = (rr == 0) ? c0 : (rr == 1) ? c1 : (rr == 2) ? c2 : c3;
            const float A  = exp2_f(acc[0][rr]);        // e^{-a_i}   (early)
            const float Fe = exp2_f(acc[1][rr]);        // e^{-a_f}   (early)
            const float G  = exp2_f(acc[2][rr]);        // e^{2 a_g}  (early)
            const float Oe = exp2_f(acc[3][rr]);        // e^{-a_o}   (early)
            const float f   = rcp_f(1.0f + Fe);         // early, off-path
            const float pm  = K2E * (G - 1.0f);         // early
            const float den = (1.0f + A) * (G + 1.0f);  // early
            const float oq  = 1.0f + Oe;                // early
            // critical path: rcp -> mul -> fma -> min -> exp2 -> mul -> rcp -> mul
            const float p = pm * rcp_f(den);
            cc = fminf(__builtin_fmaf(f, cc, p), 75.0f);
            const float E = exp2_f(cc);
            nxt[hoff(quad * 4 + rr) + j] =
                f2bf((E - 1.0f) * rcp_f((E + 1.0f) * oq));
        }

        // SW-pipeline: next step's init (xs-only, off the h path)
        const int tn = (t + 1) & CM;
        if (tn != 0) {
            const float xv0 = xs[(quad * 4 + 0) * XST + tn];
            const float xv1 = xs[(quad * 4 + 1) * XST + tn];
            const float xv2 = xs[(quad * 4 + 2) * XST + tn];
            const float xv3 = xs[(quad * 4 + 3) * XST + tn];
            #pragma unroll
            for (int t4 = 0; t4 < 4; ++t4) {
                iv[t4][0] = __builtin_fmaf(xv0, wihS[t4], biasS[t4]);
                iv[t4][1] = __builtin_fmaf(xv1, wihS[t4], biasS[t4]);
                iv[t4][2] = __builtin_fmaf(xv2, wihS[t4], biasS[t4]);
                iv[t4][3] = __builtin_fmaf(xv3, wihS[t4], biasS[t4]);
            }
        }

        unsigned short* tmp = cur; cur = nxt; nxt = tmp;
        __syncthreads();
    }

    // ---- LSTM2 (one step from zero state) ----
    {
        BF8 bw2[4][2];
        float bias2S[4];
        #pragma unroll
        for (int t4 = 0; t4 < 4; ++t4) {
            const int row = t4 * HH + j;
            #pragma unroll
            for (int kk = 0; kk < 2; ++kk)
                #pragma unroll
                for (int e = 0; e < 8; ++e) {
                    const int k = kk * 32 + quad * 8 + e;
                    bw2[t4][kk].u[e] = f2bf((jv && k < HH) ? wih2[row * HH + k] : 0.0f);
                }
            bias2S[t4] = jv ? (bih2[row] + bhh2[row]) : 0.0f;
        }
        const bf16x8 a0 = *(const bf16x8*)&cur[rdA];
        const bf16x8 a1 = *(const bf16x8*)&cur[rdB];
        f32x4 acc2[4];
        #pragma unroll
        for (int t4 = 0; t4 < 4; ++t4) {
            acc2[t4][0] = bias2S[t4]; acc2[t4][1] = bias2S[t4];
            acc2[t4][2] = bias2S[t4]; acc2[t4][3] = bias2S[t4];
        }
        #pragma unroll
        for (int t4 = 0; t4 < 4; ++t4) {
            acc2[t4] = __builtin_amdgcn_mfma_f32_16x16x32_bf16(a0, bw2[t4][0].v, acc2[t4], 0, 0, 0);
            acc2[t4] = __builtin_amdgcn_mfma_f32_16x16x32_bf16(a1, bw2[t4][1].v, acc2[t4], 0, 0, 0);
        }
        #pragma unroll
        for (int r = 0; r < 4; ++r) {
            const float i2 = sigm(acc2[0][r]);
            const float g2 = tanh_f(acc2[2][r]);
            const float o2 = sigm(acc2[3][r]);
            const float cc = i2 * g2;           // f*c0 vanishes (c0 = 0)
            if (jv) h2s[(quad * 4 + r) * 52 + j] = o2 * tanh_f(cc);
        }
    }
    __syncthreads();

    // ---- FC: out[b] = h2[b] . fcW + fcb ----
    {
        const int b = tid >> 4, l = tid & 15;
        float p = 0.f;
        for (int jj = l; jj < HH; jj += 16)
            p = __builtin_fmaf(h2s[b * 52 + jj], fcw[jj], p);
        #pragma unroll
        for (int off = 8; off > 0; off >>= 1) p += __shfl_xor(p, off, 16);
        if (l == 0) out[b0 + b] = p + fcb[0];
    }
}

extern "C" void kernel_launch(void* const* d_in, const int* in_sizes, int n_in,
                              void* d_out, int out_size, void* d_ws, size_t ws_size,
                              hipStream_t stream) {
    lstm_mfma_kernel<<<NB, 256, 0, stream>>>(
        (const float*)d_in[0],
        (const float*)d_in[1], (const float*)d_in[2],
        (const float*)d_in[3], (const float*)d_in[4],
        (const float*)d_in[5],
        (const float*)d_in[7], (const float*)d_in[8],
        (const float*)d_in[9], (const float*)d_in[10],
        (float*)d_out);
}